// Round 22
// baseline (31.110 us; speedup 1.0000x reference)
//
#include <hip/hip_runtime.h>

#define NPTS 4096
#define N0V  10242
#define EPSV 1e-5f
#define SLOTS 16
#define FXS 16777216.0   // 2^24 fixed-point scale

typedef unsigned short ushortT;
typedef unsigned long long ullT;
typedef __attribute__((ext_vector_type(8))) short short8;
typedef __attribute__((ext_vector_type(4))) float f32x4;

__device__ __forceinline__ float fmul(float a,float b){return __fmul_rn(a,b);}
__device__ __forceinline__ float fadd(float a,float b){return __fadd_rn(a,b);}
__device__ __forceinline__ float fsub(float a,float b){return __fsub_rn(a,b);}

__device__ __forceinline__ ushortT f2bf(float x){
  unsigned u = __float_as_uint(x);
  u = (u + 0x7fffu + ((u>>16)&1u)) >> 16;
  return (ushortT)u;
}
__device__ __forceinline__ float bf2f(ushortT u){
  return __uint_as_float(((unsigned)u) << 16);
}

// ---- per-wave 16x16 MFMA tile ----
template<int NS>
__device__ __forceinline__ void tile_mm(const ushortT* xa, const ushortT* wt, int wstr,
    int li, int hi, int rt, int colg, f32x4& acc)
{
  acc = (f32x4){0.f,0.f,0.f,0.f};
  const ushortT* wbp = wt + colg*wstr + hi*8;
  const ushortT* xap = xa + (rt*16 + li)*168 + hi*8;
  #pragma unroll
  for (int s=0;s<NS;s++){
    short8 bb = *(const short8*)(wbp + s*32);
    short8 a0 = *(const short8*)(xap + s*32);
    acc = __builtin_amdgcn_mfma_f32_16x16x32_bf16(a0, bb, acc, 0,0,0);
  }
}

// ---- per-wave partials -> DETERMINISTIC fixed-point int64 atomicAdd into 16 slots ----
__device__ __forceinline__ void tile_partials(const f32x4& acc, ullT* __restrict__ slotL,
                                              int blk, int lane, int colg)
{
  float s1=0.f, s2=0.f;
  #pragma unroll
  for (int r=0;r<4;r++){ s1 += acc[r]; s2 = fmaf(acc[r],acc[r],s2); }
  s1 += __shfl_xor(s1,16); s1 += __shfl_xor(s1,32);
  s2 += __shfl_xor(s2,16); s2 += __shfl_xor(s2,32);
  if (lane < 16){
    ullT* sl = slotL + (blk & (SLOTS-1))*256;
    long long q1 = __double2ll_rn((double)s1 * FXS);
    long long q2 = __double2ll_rn((double)s2 * FXS);
    atomicAdd(&sl[colg],       (ullT)q1);
    atomicAdd(&sl[128 + colg], (ullT)q2);
  }
}

// ---- stats from previous kernel's slots: plain int64 loads (inter-dispatch barrier = sync) ----
__device__ __forceinline__ void slot_stats(const ullT* __restrict__ slotL,
    const float* __restrict__ g, const float* __restrict__ be,
    float* red2, float* stS, float* stB, int t)
{
  if (t < 256){
    long long v = 0;
    #pragma unroll
    for (int s=0;s<SLOTS;s++) v += (long long)slotL[s*256 + t];
    red2[t] = (float)((double)v * (1.0/FXS));
  }
  __syncthreads();
  if (t < 128){
    float S = red2[t], Q = red2[128 + t];
    float mean = S * (1.0f/8192.0f);
    float var  = Q * (1.0f/8192.0f) - mean*mean;
    float inv  = 1.0f / __fsqrt_rn(var + EPSV);
    float sc = g[t]*inv;
    stS[t] = sc;
    stB[t] = be[t] - mean*sc;
  }
  __syncthreads();
}

// ---- DMA a linear bf16 weight block global->LDS (nchunks x 1KB) ----
__device__ __forceinline__ void dma_w(const ushortT* __restrict__ src, ushortT* dst,
                                      int nchunks, int w, int lane)
{
  const char* s = (const char*)src;
  char* d = (char*)dst;
  for (int i = w; i < nchunks; i += 16){
    __builtin_amdgcn_global_load_lds(
        (const __attribute__((address_space(1))) void*)(s + (size_t)i*1024 + (size_t)lane*16),
        (__attribute__((address_space(3))) void*)(d + (size_t)i*1024), 16, 0, 0);
  }
}

// ================= k_l0: dual-row shared-vertex scan + gather + wt0 pack + L0 MFMA ============
__global__ __launch_bounds__(1024) void k_l0(
    const float* __restrict__ orig, const float* __restrict__ proj,
    const float* __restrict__ vertex, const int* __restrict__ nidx,
    const float* __restrict__ W0, const float* __restrict__ b0,
    const float* __restrict__ W1, const float* __restrict__ W2,
    ullT* __restrict__ slot0, ullT* __restrict__ slotZ,
    ushortT* __restrict__ wpkg, ushortT* __restrict__ y0)
{
  __shared__ __align__(16) ushortT wt[128*168];
  __shared__ __align__(16) ushortT xa[32*168];

  const int t    = threadIdx.x;
  const int blk  = blockIdx.x;
  const int lane = t & 63;
  const int w    = t >> 6;
  const int b    = blk >> 7;
  const int n0   = (blk & 127) * 32;
  const int li   = lane & 15;
  const int hi   = lane >> 4;
  const int rt   = w >> 3;
  const int colg = (w & 7)*16 + li;

  // zero slot1+slot2 (8 blocks x 1024 ullT = 8192 int64)
  if (blk < 8) slotZ[blk*1024 + t] = 0ULL;

  // pack W1/W2 -> global bf16 [2][128][136] (136 els per block)
  if (t < 136){
    int u = blk*136 + t;
    int L = u / 17408, q = u - L*17408;
    int o = q / 136, k = q - o*136;
    float v = 0.f;
    if (k < 128) v = (L == 0) ? W1[o*128 + k] : W2[o*128 + k];
    wpkg[u] = f2bf(v);
  }

  // pack wt0 f32->bf16 into LDS
  for (int u = t; u < 21504; u += 1024){
    int o = u/168, k = u - o*168;
    wt[u] = f2bf((k < 147) ? W0[o*147 + k] : 0.f);
  }

  // dual-row scan: both of this wave's rows share each vertex chunk load
  {
    float v0x=vertex[0], v0y=vertex[1], v0z=vertex[2];
    float r  = __fsqrt_rn(fadd(fadd(fmul(v0x,v0x),fmul(v0y,v0y)),fmul(v0z,v0z)));
    float rr = fmul(r,r);
    int j0 = nidx[0];
    float ax=vertex[3*j0], ay=vertex[3*j0+1], az=vertex[3*j0+2];
    float dx=fsub(v0x,ax), dy=fsub(v0y,ay), dz=fsub(v0z,az);
    float t2 = fadd(fadd(fmul(dx,dx),fmul(dy,dy)),fmul(dz,dz));

    const int rowA = w*2, rowB = w*2 + 1;
    const int nA = n0 + rowA, nB = n0 + rowB;

    const float* obA = orig + (b*19)*NPTS + nA;
    float xA=obA[0], yA=obA[NPTS], zA=obA[2*NPTS];
    float nrmA = __fsqrt_rn(fadd(fadd(fmul(xA,xA),fmul(yA,yA)),fmul(zA,zA)));
    float sA = __fdiv_rn(r,nrmA);
    float pxA=fmul(xA,sA), pyA=fmul(yA,sA), pzA=fmul(zA,sA);

    const float* obB = orig + (b*19)*NPTS + nB;
    float xB=obB[0], yB=obB[NPTS], zB=obB[2*NPTS];
    float nrmB = __fsqrt_rn(fadd(fadd(fmul(xB,xB),fmul(yB,yB)),fmul(zB,zB)));
    float sB = __fdiv_rn(r,nrmB);
    float pxB=fmul(xB,sB), pyB=fmul(yB,sB), pzB=fmul(zB,sB);

    int firstA=0, hasA=0, firstB=0, hasB=0;
    for (int c0=0; c0<N0V; c0+=256){
      int m0=min(c0+lane,N0V-1), m1=min(c0+lane+64,N0V-1),
          m2=min(c0+lane+128,N0V-1), m3=min(c0+lane+192,N0V-1);
      float a0x=vertex[3*m0],a0y=vertex[3*m0+1],a0z=vertex[3*m0+2];
      float a1x=vertex[3*m1],a1y=vertex[3*m1+1],a1z=vertex[3*m1+2];
      float a2x=vertex[3*m2],a2y=vertex[3*m2+1],a2z=vertex[3*m2+2];
      float a3x=vertex[3*m3],a3y=vertex[3*m3+1],a3z=vertex[3*m3+2];
      float v20=fadd(fadd(fmul(a0x,a0x),fmul(a0y,a0y)),fmul(a0z,a0z));
      float v21=fadd(fadd(fmul(a1x,a1x),fmul(a1y,a1y)),fmul(a1z,a1z));
      float v22=fadd(fadd(fmul(a2x,a2x),fmul(a2y,a2y)),fmul(a2z,a2z));
      float v23=fadd(fadd(fmul(a3x,a3x),fmul(a3y,a3y)),fmul(a3z,a3z));
      bool in0 = (c0+lane    <N0V), in1 = (c0+lane+64 <N0V),
           in2 = (c0+lane+128<N0V), in3 = (c0+lane+192<N0V);

      if (!hasA){
        float d0=fadd(fadd(fmul(pxA,a0x),fmul(pyA,a0y)),fmul(pzA,a0z));
        float d1=fadd(fadd(fmul(pxA,a1x),fmul(pyA,a1y)),fmul(pzA,a1z));
        float d2=fadd(fadd(fmul(pxA,a2x),fmul(pyA,a2y)),fmul(pzA,a2z));
        float d3=fadd(fadd(fmul(pxA,a3x),fmul(pyA,a3y)),fmul(pzA,a3z));
        bool h0 = in0 && (fsub(fadd(rr,v20),fmul(2.0f,d0)) <= t2);
        bool h1 = in1 && (fsub(fadd(rr,v21),fmul(2.0f,d1)) <= t2);
        bool h2 = in2 && (fsub(fadd(rr,v22),fmul(2.0f,d2)) <= t2);
        bool h3 = in3 && (fsub(fadd(rr,v23),fmul(2.0f,d3)) <= t2);
        unsigned long long bal;
        if      ((bal=__ballot(h0))){ firstA=c0     +__builtin_ctzll(bal); hasA=1; }
        else if ((bal=__ballot(h1))){ firstA=c0+ 64+__builtin_ctzll(bal); hasA=1; }
        else if ((bal=__ballot(h2))){ firstA=c0+128+__builtin_ctzll(bal); hasA=1; }
        else if ((bal=__ballot(h3))){ firstA=c0+192+__builtin_ctzll(bal); hasA=1; }
      }
      if (!hasB){
        float d0=fadd(fadd(fmul(pxB,a0x),fmul(pyB,a0y)),fmul(pzB,a0z));
        float d1=fadd(fadd(fmul(pxB,a1x),fmul(pyB,a1y)),fmul(pzB,a1z));
        float d2=fadd(fadd(fmul(pxB,a2x),fmul(pyB,a2y)),fmul(pzB,a2z));
        float d3=fadd(fadd(fmul(pxB,a3x),fmul(pyB,a3y)),fmul(pzB,a3z));
        bool h0 = in0 && (fsub(fadd(rr,v20),fmul(2.0f,d0)) <= t2);
        bool h1 = in1 && (fsub(fadd(rr,v21),fmul(2.0f,d1)) <= t2);
        bool h2 = in2 && (fsub(fadd(rr,v22),fmul(2.0f,d2)) <= t2);
        bool h3 = in3 && (fsub(fadd(rr,v23),fmul(2.0f,d3)) <= t2);
        unsigned long long bal;
        if      ((bal=__ballot(h0))){ firstB=c0     +__builtin_ctzll(bal); hasB=1; }
        else if ((bal=__ballot(h1))){ firstB=c0+ 64+__builtin_ctzll(bal); hasB=1; }
        else if ((bal=__ballot(h2))){ firstB=c0+128+__builtin_ctzll(bal); hasB=1; }
        else if ((bal=__ballot(h3))){ firstB=c0+192+__builtin_ctzll(bal); hasB=1; }
      }
      if (hasA && hasB) break;
    }

    // gather both rows
    const float* pb = proj + (long)b*128*N0V;
    {
      ushortT* rowp = xa + rowA*168;
      const float* prA = pb + (long)firstA*128;   // note: proj is [c][m]; keep original layout
      #pragma unroll
      for (int k=0;k<3;k++){
        int idx = lane + k*64;
        if (idx < 168){
          float v;
          if (idx < 19)        v = orig[(b*19+idx)*NPTS + nA];
          else if (idx < 147)  v = hasA ? pb[(long)(idx-19)*N0V + firstA] : 0.0f;
          else                 v = 0.0f;
          rowp[idx] = f2bf(v);
        }
      }
      (void)prA;
    }
    {
      ushortT* rowp = xa + rowB*168;
      #pragma unroll
      for (int k=0;k<3;k++){
        int idx = lane + k*64;
        if (idx < 168){
          float v;
          if (idx < 19)        v = orig[(b*19+idx)*NPTS + nB];
          else if (idx < 147)  v = hasB ? pb[(long)(idx-19)*N0V + firstB] : 0.0f;
          else                 v = 0.0f;
          rowp[idx] = f2bf(v);
        }
      }
    }
  }
  __syncthreads();

  f32x4 acc;
  tile_mm<5>(xa, wt, 168, li, hi, rt, colg, acc);
  float bo = b0[colg];
  #pragma unroll
  for (int r=0;r<4;r++) acc[r] += bo;
  tile_partials(acc, slot0, blk, lane, colg);
  #pragma unroll
  for (int r=0;r<4;r++)
    y0[(long)(b*4096 + n0 + rt*16 + hi*4 + r)*128 + colg] = f2bf(acc[r]);
}

// ================= k_lmid: DMA wt + stats(prev slots) + affine + MFMA + partials + y out ======
__global__ __launch_bounds__(1024) void k_lmid(
    const ushortT* __restrict__ yin, const ullT* __restrict__ slotPrev,
    const float* __restrict__ g, const float* __restrict__ be,
    const ushortT* __restrict__ wpk, const float* __restrict__ bias,
    ullT* __restrict__ slotCur, ushortT* __restrict__ yout)
{
  __shared__ __align__(16) ushortT wt[128*136];
  __shared__ __align__(16) ushortT xa[32*168];
  __shared__ float red2[256];
  __shared__ float stS[128];
  __shared__ float stB[128];

  const int t    = threadIdx.x;
  const int blk  = blockIdx.x;
  const int lane = t & 63;
  const int w    = t >> 6;
  const int n0   = blk * 32;
  const int li   = lane & 15;
  const int hi   = lane >> 4;
  const int rt   = w >> 3;
  const int colg = (w & 7)*16 + li;

  dma_w(wpk, wt, 34, w, lane);

  for (int u = t; u < 1280; u += 1024){
    int row = u/40, c = 128 + (u - row*40);
    xa[row*168 + c] = 0;
  }
  slot_stats(slotPrev, g, be, red2, stS, stB, t);

  if (t < 512){
    int row = t >> 4, c0 = (t & 15) * 8;
    short8 yv = *(const short8*)(yin + (long)(n0+row)*128 + c0);
    short8 xv;
    #pragma unroll
    for (int j=0;j<8;j++){
      float f = bf2f((ushortT)yv[j]);
      f = fmaxf(fmaf(f, stS[c0+j], stB[c0+j]), 0.f);
      xv[j] = (short)f2bf(f);
    }
    *(short8*)(xa + row*168 + c0) = xv;
  }
  __syncthreads();

  f32x4 acc;
  tile_mm<4>(xa, wt, 136, li, hi, rt, colg, acc);
  float bo = bias[colg];
  #pragma unroll
  for (int r=0;r<4;r++) acc[r] += bo;
  tile_partials(acc, slotCur, blk, lane, colg);
  #pragma unroll
  for (int r=0;r<4;r++)
    yout[(long)(n0 + rt*16 + hi*4 + r)*128 + colg] = f2bf(acc[r]);
}

// ================= k_out: stats(L2 slots) + affine/relu + transpose + store ==================
__global__ __launch_bounds__(1024) void k_out(
    const ushortT* __restrict__ yin, const ullT* __restrict__ slotPrev,
    const float* __restrict__ g, const float* __restrict__ be,
    float* __restrict__ out)
{
  __shared__ float ft[32*132];
  __shared__ float red2[256];
  __shared__ float stS[128];
  __shared__ float stB[128];

  const int t   = threadIdx.x;
  const int blk = blockIdx.x;
  const int b   = blk >> 7;
  const int n0  = (blk & 127) * 32;

  slot_stats(slotPrev, g, be, red2, stS, stB, t);

  if (t < 512){
    int row = t >> 4, c0 = (t & 15) * 8;
    short8 yv = *(const short8*)(yin + (long)(b*4096 + n0 + row)*128 + c0);
    #pragma unroll
    for (int j=0;j<8;j++)
      ft[row*132 + c0 + j] = fmaxf(fmaf(bf2f((ushortT)yv[j]), stS[c0+j], stB[c0+j]), 0.f);
  }
  __syncthreads();

  float* ob = out + (long)b*128*NPTS + n0;
  {
    int oo = t >> 3, jj = (t & 7) * 4;
    float4 v;
    v.x = ft[(jj  )*132 + oo];
    v.y = ft[(jj+1)*132 + oo];
    v.z = ft[(jj+2)*132 + oo];
    v.w = ft[(jj+3)*132 + oo];
    *(float4*)(ob + (long)oo*NPTS + jj) = v;
  }
}

extern "C" void kernel_launch(void* const* d_in, const int* in_sizes, int n_in,
                              void* d_out, int out_size, void* d_ws, size_t ws_size,
                              hipStream_t stream)
{
  const float* orig   = (const float*)d_in[0];
  const float* proj   = (const float*)d_in[1];
  const float* vertex = (const float*)d_in[2];
  const int*   nidx   = (const int*)d_in[3];
  const float* W0 = (const float*)d_in[4];
  const float* b0 = (const float*)d_in[5];
  const float* g0 = (const float*)d_in[6];
  const float* be0= (const float*)d_in[7];
  const float* W1 = (const float*)d_in[8];
  const float* b1 = (const float*)d_in[9];
  const float* g1 = (const float*)d_in[10];
  const float* be1= (const float*)d_in[11];
  const float* W2 = (const float*)d_in[12];
  const float* b2 = (const float*)d_in[13];
  const float* g2 = (const float*)d_in[14];
  const float* be2= (const float*)d_in[15];
  float* out = (float*)d_out;

  float*   ws    = (float*)d_ws;
  ullT*    slots = (ullT*)ws;                  // 3 x 16 x 256 int64
  ullT*    slot0 = slots;
  ullT*    slot1 = slots + 4096;
  ullT*    slot2 = slots + 8192;
  ushortT* wpkg  = (ushortT*)(ws + 24576);     // 34816 ush
  ushortT* yA    = (ushortT*)(ws + 41984);     // 8192*128 ush
  ushortT* yB    = yA + 8192*128;

  hipMemsetAsync(d_ws, 0, 4096*sizeof(ullT), stream);   // slot0; slot1/2 zeroed by k_l0

  k_l0  <<<256, 1024, 0, stream>>>(orig, proj, vertex, nidx, W0, b0, W1, W2,
                                   slot0, slot1, wpkg, yA);
  k_lmid<<<256, 1024, 0, stream>>>(yA, slot0, g0, be0, wpkg,         b1, slot1, yB);
  k_lmid<<<256, 1024, 0, stream>>>(yB, slot1, g1, be1, wpkg + 17408, b2, slot2, yA);
  k_out <<<256, 1024, 0, stream>>>(yA, slot2, g2, be2, out);
}